// Round 16
// baseline (101.845 us; speedup 1.0000x reference)
//
#include <hip/hip_runtime.h>

#define B_ 8
#define T_ 256
#define U_ 101
#define V_ 512
#define UM1 (U_ - 1)
#define DSTR 128    // floats per diagonal row (u-index stride)
#define DALLOC 360  // diagonals allocated (max row read = 356)
#define CH 32       // DP stages per LDS chunk
#define NCHD 6      // chunks per direction (6*32 = 192 >= ceil(355/2)+1)
#define CS 512.0f   // 2^9 per-step growth factor baked into staged probs
#define NUNITS (B_ * T_ * U_ / 2)  // 103,424 row-pairs
#define LSE_GRID 2048              // 8 blocks/CU, grid-stride sweep
#define LOG2E 1.4426950408889634f
#define LN2 0.6931471805599453f

typedef float floatx4 __attribute__((ext_vector_type(4)));
typedef float floatx2 __attribute__((ext_vector_type(2)));

// DPP move with bound_ctrl=1 (out-of-range lanes read 0).
#define DPPMOV(x, ctrl)                                                     \
  __int_as_float(__builtin_amdgcn_update_dpp(0, __float_as_int(x), (ctrl),  \
                                             0xF, 0xF, true))

__device__ __forceinline__ float readlane63(float x) {
  return __int_as_float(__builtin_amdgcn_readlane(__float_as_int(x), 63));
}
// Full-wave sum via DPP (VALU-latency); result valid in lane 63.
__device__ __forceinline__ float wave_sum63(float x) {
  x += DPPMOV(x, 0x111);  // row_shr:1
  x += DPPMOV(x, 0x112);  // row_shr:2
  x += DPPMOV(x, 0x114);  // row_shr:4
  x += DPPMOV(x, 0x118);  // row_shr:8
  x += DPPMOV(x, 0x142);  // row_bcast:15
  x += DPPMOV(x, 0x143);  // row_bcast:31
  return x;
}
// Full-wave max via DPP (nonnegative inputs); result valid in lane 63.
__device__ __forceinline__ float wave_max63(float x) {
  x = fmaxf(x, DPPMOV(x, 0x111));
  x = fmaxf(x, DPPMOV(x, 0x112));
  x = fmaxf(x, DPPMOV(x, 0x114));
  x = fmaxf(x, DPPMOV(x, 0x118));
  x = fmaxf(x, DPPMOV(x, 0x142));
  x = fmaxf(x, DPPMOV(x, 0x143));
  return x;
}
// lane n <- lane n-1 (DPP wave_shr:1). Lane 0 <- 0 (additive identity).
__device__ __forceinline__ float wave_shr1_zero(float x) {
  int r = __builtin_amdgcn_update_dpp(0, __float_as_int(x), 0x138, 0xF, 0xF,
                                      false);
  return __int_as_float(r);
}
// lane n <- lane n+1 (DPP wave_shl:1). Lane 63 <- 0.
__device__ __forceinline__ float wave_shl1_zero(float x) {
  int r = __builtin_amdgcn_update_dpp(0, __float_as_int(x), 0x130, 0xF, 0xF,
                                      false);
  return __int_as_float(r);
}

// Grid-stride lse: 2048 blocks x 256 threads (8 blocks/CU, 32 waves/CU);
// each wave sweeps ~13 row-pairs (2 rows of V=512 logits per unit, linear in
// acts memory order). Max-free softmax denominator (DPP reduction); stores
// LINEAR-domain scaled probs diagonal-major:
//   blankD[b][t+u+1][u]   = e^blank_logit / sum * 2^9
//   emitD [b][t+u+1][u+1] = e^label_logit / sum * 2^9
// Unwritten slots are pre-zeroed (memset) = additive identity.
__global__ __launch_bounds__(256) void lse_kernel(
    const float* __restrict__ acts, const int* __restrict__ labels,
    float* __restrict__ blankD, float* __restrict__ emitD) {
  const int lane = threadIdx.x & 63;
  for (int wv = blockIdx.x * 4 + (threadIdx.x >> 6); wv < NUNITS;
       wv += LSE_GRID * 4) {
    const int r0 = wv * 2;  // row = (b*T + t)*U + u
    const int r1 = r0 + 1;
    const floatx4* p0 = (const floatx4*)(acts + (size_t)r0 * V_);
    const floatx4* p1 = (const floatx4*)(acts + (size_t)r1 * V_);
    floatx4 a0 = p0[lane];
    floatx4 a1 = p0[lane + 64];
    floatx4 c0 = p1[lane];
    floatx4 c1 = p1[lane + 64];
    float s0 = __builtin_exp2f(a0.x * LOG2E) + __builtin_exp2f(a0.y * LOG2E) +
               __builtin_exp2f(a0.z * LOG2E) + __builtin_exp2f(a0.w * LOG2E) +
               __builtin_exp2f(a1.x * LOG2E) + __builtin_exp2f(a1.y * LOG2E) +
               __builtin_exp2f(a1.z * LOG2E) + __builtin_exp2f(a1.w * LOG2E);
    float s1 = __builtin_exp2f(c0.x * LOG2E) + __builtin_exp2f(c0.y * LOG2E) +
               __builtin_exp2f(c0.z * LOG2E) + __builtin_exp2f(c0.w * LOG2E) +
               __builtin_exp2f(c1.x * LOG2E) + __builtin_exp2f(c1.y * LOG2E) +
               __builtin_exp2f(c1.z * LOG2E) + __builtin_exp2f(c1.w * LOG2E);
    s0 = readlane63(wave_sum63(s0));  // uniform across the wave
    s1 = readlane63(wave_sum63(s1));

#define EMIT_ROW(r, v0, v1, ssum)                                             \
    {                                                                         \
      const int u = (r) % U_;                                                 \
      const int bt = (r) / U_;                                                \
      const int t = bt % T_;                                                  \
      const int b = bt / T_;                                                  \
      float emitv = 0.0f;                                                     \
      if (u < UM1) {                                                          \
        int e = labels[b * UM1 + u]; /* in [1, V) */                          \
        floatx4 sel = (e < 256) ? v0 : v1;                                    \
        int k = e & 3;                                                        \
        float cand =                                                          \
            (k == 0) ? sel.x : (k == 1) ? sel.y : (k == 2) ? sel.z : sel.w;   \
        emitv = __shfl(cand, (e & 255) >> 2);                                 \
      }                                                                       \
      if (lane == 0) {                                                        \
        const float rs = CS * __builtin_amdgcn_rcpf(ssum);                    \
        blankD[((size_t)b * DALLOC + (t + u + 1)) * DSTR + u] =               \
            __builtin_exp2f(v0.x * LOG2E) * rs;                               \
        if (u < UM1)                                                          \
          emitD[((size_t)b * DALLOC + (t + u + 1)) * DSTR + (u + 1)] =        \
              __builtin_exp2f(emitv * LOG2E) * rs;                            \
      }                                                                       \
    }

    EMIT_ROW(r0, a0, a1, s0)
    EMIT_ROW(r1, c0, c1, s1)
#undef EMIT_ROW
  }
}

// Bidirectional linear-domain DP with fused combine. Blocks 0..7: forward
// alpha; 8..15: backward beta. Each block writes its meeting state; the
// SECOND finisher per example (flag handshake, order-independent result)
// computes the final loss. Recurrence chain is pure dpp+mul+fma.
__global__ __launch_bounds__(64, 1) void dp_kernel(
    const float* __restrict__ blankD, const float* __restrict__ emitD,
    const int* __restrict__ act_lens, const int* __restrict__ label_lens,
    float* __restrict__ stateA, float* __restrict__ stateB,
    int* __restrict__ flags, float* __restrict__ out) {
  __shared__ float lds[2][2][CH][DSTR];  // 128 KB
  const int bid = blockIdx.x;
  const int b = bid & 7;
  const bool fwd = (bid < 8);
  const int lane = threadIdx.x;
  const int tl1 = act_lens[b] - 1;
  const int ulen = label_lens[b];
  const int dtar = tl1 + ulen;
  const int dmid = dtar >> 1;
  const floatx4* g4B = (const floatx4*)(blankD + (size_t)b * DALLOC * DSTR);
  const floatx4* g4E = (const floatx4*)(emitD + (size_t)b * DALLOC * DSTR);
  floatx4 rB[16], rE[16];
  float xE, xO, S = 0.0f, cE = 0.0f, cO = 0.0f, capS = 0.0f;

  if (fwd) {
    // ---------------- forward: alpha; capture at diagonal dmid ------------
    const int ccap = (dmid - 1) >> 5;  // chunk containing d == dmid
#pragma unroll
    for (int j = 0; j < 16; ++j) {
      rB[j] = g4B[32 + j * 64 + lane];  // chunk 0 = rows 1..32
      rE[j] = g4E[32 + j * 64 + lane];
    }
    {
      floatx4* lB4 = (floatx4*)&lds[0][0][0][0];
      floatx4* lE4 = (floatx4*)&lds[0][1][0][0];
#pragma unroll
      for (int j = 0; j < 16; ++j) {
        lB4[j * 64 + lane] = rB[j];
        lE4[j * 64 + lane] = rE[j];
      }
    }
    xE = (lane == 0) ? 1.0f : 0.0f;  // alpha[0,0] = 1 at diagonal 0
    xO = 0.0f;
    for (int c = 0; c < NCHD; ++c) {
      const int buf = c & 1;
      const int nb = ((c + 1) * CH + 1) * 32;
#pragma unroll
      for (int j = 0; j < 16; ++j) {
        rB[j] = g4B[(size_t)nb + j * 64 + lane];
        rE[j] = g4E[(size_t)nb + j * 64 + lane];
      }
      const floatx2* lB2 = (const floatx2*)&lds[buf][0][0][0];
      const floatx2* lE2 = (const floatx2*)&lds[buf][1][0][0];
      floatx2 pB[8], pE[8];
#pragma unroll
      for (int k = 0; k < 8; ++k) {
        pB[k] = lB2[k * 64 + lane];
        pE[k] = lE2[k * 64 + lane];
      }
      const int dbase = c * CH + 1;
#pragma unroll
      for (int k = 0; k < CH; ++k) {
        const int d = dbase + k;
        const floatx2 Bv = pB[k & 7];
        const floatx2 Ev = pE[k & 7];
        if (k + 8 < CH) {
          pB[k & 7] = lB2[(k + 8) * 64 + lane];
          pE[k & 7] = lE2[(k + 8) * 64 + lane];
        }
        const float xm1E = wave_shr1_zero(xO);  // col uE-1, prev diagonal
        const float nxE = __builtin_fmaf(xE, Bv.x, xm1E * Ev.x);
        const float nxO = __builtin_fmaf(xO, Bv.y, xE * Ev.y);
        const bool cap = (d == dmid);  // off-chain capture
        cE = cap ? nxE : cE;
        cO = cap ? nxO : cO;
        xE = nxE;
        xO = nxO;
      }
      if (c == ccap) capS = S;  // scales applied before the capture chunk
      float m = readlane63(wave_max63(fmaxf(xE, xO)));
      if (m > 0.0f) {
        const float ex = floorf(__builtin_log2f(m));
        const float sc = __builtin_exp2f(-ex);
        xE *= sc;
        xO *= sc;
        S += ex;
      }
      floatx4* wB4 = (floatx4*)&lds[buf ^ 1][0][0][0];
      floatx4* wE4 = (floatx4*)&lds[buf ^ 1][1][0][0];
#pragma unroll
      for (int j = 0; j < 16; ++j) {
        wB4[j * 64 + lane] = rB[j];
        wE4[j * 64 + lane] = rE[j];
      }
    }
    float* sA = stateA + b * 132;
    ((floatx2*)sA)[lane] = floatx2{cE, cO};
    if (lane == 0) sA[128] = capS;
  } else {
    // ---------------- backward: beta; capture at stage smax ---------------
    const int smax = dtar - 1 - dmid;
    const int ccap = smax >> 5;
    const int R00 = dtar - 31;  // chunk 0 rows [dtar-31, dtar]
#pragma unroll
    for (int j = 0; j < 16; ++j) {
      rB[j] = g4B[(size_t)R00 * 32 + j * 64 + lane];
      rE[j] = g4E[(size_t)R00 * 32 + j * 64 + lane];
    }
    {
      floatx4* lB4 = (floatx4*)&lds[0][0][0][0];
      floatx4* lE4 = (floatx4*)&lds[0][1][0][0];
#pragma unroll
      for (int j = 0; j < 16; ++j) {
        lB4[j * 64 + lane] = rB[j];
        lE4[j * 64 + lane] = rE[j];
      }
    }
    const float seed = blankD[((size_t)b * DALLOC + dtar + 1) * DSTR + ulen];
    xE = (lane == (ulen >> 1) && !(ulen & 1)) ? seed : 0.0f;
    xO = (lane == (ulen >> 1) && (ulen & 1)) ? seed : 0.0f;
    for (int c = 0; c < NCHD; ++c) {
      const int buf = c & 1;
      const int R0n = max(R00 - 32 * (c + 1), 0);
#pragma unroll
      for (int j = 0; j < 16; ++j) {
        rB[j] = g4B[(size_t)R0n * 32 + j * 64 + lane];
        rE[j] = g4E[(size_t)R0n * 32 + j * 64 + lane];
      }
      const floatx2* lB2 = (const floatx2*)&lds[buf][0][0][0];
      const floatx2* lE2 = (const floatx2*)&lds[buf][1][0][0];
      floatx2 pB[8], pE[8];
#pragma unroll
      for (int k = 0; k < 8; ++k) {  // slots descending: 31..24
        pB[k] = lB2[(31 - k) * 64 + lane];
        pE[k] = lE2[(31 - k) * 64 + lane];
      }
#pragma unroll
      for (int k = 0; k < CH; ++k) {
        const int s = c * CH + k;
        const floatx2 Bv = pB[k & 7];
        const floatx2 Ev = pE[k & 7];
        if (k + 8 < CH) {
          pB[k & 7] = lB2[(31 - (k + 8)) * 64 + lane];
          pE[k & 7] = lE2[(31 - (k + 8)) * 64 + lane];
        }
        const float tO = wave_shl1_zero(Ev.x * xE);  // lane l+1: Em*beta
        const float nxE = __builtin_fmaf(xE, Bv.x, Ev.y * xO);
        const float nxO = __builtin_fmaf(xO, Bv.y, tO);
        const bool cap = (s == smax);  // off-chain capture
        cE = cap ? nxE : cE;
        cO = cap ? nxO : cO;
        xE = nxE;
        xO = nxO;
      }
      if (c == ccap) capS = S;
      float m = readlane63(wave_max63(fmaxf(xE, xO)));
      if (m > 0.0f) {
        const float ex = floorf(__builtin_log2f(m));
        const float sc = __builtin_exp2f(-ex);
        xE *= sc;
        xO *= sc;
        S += ex;
      }
      floatx4* wB4 = (floatx4*)&lds[buf ^ 1][0][0][0];
      floatx4* wE4 = (floatx4*)&lds[buf ^ 1][1][0][0];
#pragma unroll
      for (int j = 0; j < 16; ++j) {
        wB4[j * 64 + lane] = rB[j];
        wE4[j * 64 + lane] = rE[j];
      }
    }
    float* sB = stateB + b * 132;
    ((floatx2*)sB)[lane] = floatx2{cE, cO};
    if (lane == 0) sB[128] = capS;
  }

  // ---- fused combine: second finisher per example does the dot + log ----
  __threadfence();  // release: state visible device-wide before flag bump
  int old = 0;
  if (lane == 0) old = atomicAdd(&flags[b], 1);
  old = __shfl(old, 0);
  if (old == 1) {
    __threadfence();  // acquire: other block's state now safe to read
    const float* sA = stateA + b * 132;
    const float* sB = stateB + b * 132;
    const floatx2 a = ((const floatx2*)sA)[lane];
    const floatx2 bb = ((const floatx2*)sB)[lane];
    float p = readlane63(wave_sum63(a.x * bb.x + a.y * bb.y));
    if (lane == 0) {
      out[b] = -((__builtin_log2f(p) + sA[128] + sB[128] -
                  9.0f * (float)(dtar + 1)) *
                 LN2);
    }
  }
}

extern "C" void kernel_launch(void* const* d_in, const int* in_sizes, int n_in,
                              void* d_out, int out_size, void* d_ws, size_t ws_size,
                              hipStream_t stream) {
  const float* acts = (const float*)d_in[0];
  const int* labels = (const int*)d_in[1];
  const int* act_lens = (const int*)d_in[2];
  const int* label_lens = (const int*)d_in[3];
  float* out = (float*)d_out;
  // ws layout: [flags 32 ints][blankD][emitD][stateA][stateB]
  int* flags = (int*)d_ws;
  float* blankD = (float*)d_ws + 32;                    // B*DALLOC*DSTR floats
  float* emitD = blankD + (size_t)B_ * DALLOC * DSTR;   // B*DALLOC*DSTR floats
  float* stateA = emitD + (size_t)B_ * DALLOC * DSTR;   // B*132 floats
  float* stateB = stateA + B_ * 132;                    // B*132 floats
  // Zero flags + staging arrays in one memset (flags MUST reset every call).
  hipMemsetAsync(d_ws, 0,
                 (32 + (size_t)2 * B_ * DALLOC * DSTR) * sizeof(float),
                 stream);
  lse_kernel<<<LSE_GRID, 256, 0, stream>>>(acts, labels, blankD, emitD);
  dp_kernel<<<16, 64, 0, stream>>>(blankD, emitD, act_lens, label_lens,
                                   stateA, stateB, flags, out);
}

// Round 17
// 98.532 us; speedup vs baseline: 1.0336x; 1.0336x over previous
//
#include <hip/hip_runtime.h>

#define B_ 8
#define T_ 256
#define U_ 101
#define V_ 512
#define UM1 (U_ - 1)
#define DSTR 128    // floats per diagonal row (u-index stride)
#define DALLOC 360  // diagonals allocated (max row read = 356)
#define CH 32       // DP stages per LDS chunk
#define NCHD 6      // chunks per direction (6*32 = 192 >= ceil(355/2)+1)
#define CS 512.0f   // 2^9 per-step growth factor baked into staged probs
#define LOG2E 1.4426950408889634f
#define LN2 0.6931471805599453f

typedef float floatx4 __attribute__((ext_vector_type(4)));
typedef float floatx2 __attribute__((ext_vector_type(2)));

// DPP move with bound_ctrl=1 (out-of-range lanes read 0).
#define DPPMOV(x, ctrl)                                                     \
  __int_as_float(__builtin_amdgcn_update_dpp(0, __float_as_int(x), (ctrl),  \
                                             0xF, 0xF, true))

__device__ __forceinline__ float readlane63(float x) {
  return __int_as_float(__builtin_amdgcn_readlane(__float_as_int(x), 63));
}
// Full-wave sum via DPP (VALU-latency); result valid in lane 63.
__device__ __forceinline__ float wave_sum63(float x) {
  x += DPPMOV(x, 0x111);  // row_shr:1
  x += DPPMOV(x, 0x112);  // row_shr:2
  x += DPPMOV(x, 0x114);  // row_shr:4
  x += DPPMOV(x, 0x118);  // row_shr:8
  x += DPPMOV(x, 0x142);  // row_bcast:15
  x += DPPMOV(x, 0x143);  // row_bcast:31
  return x;
}
// Full-wave max via DPP (nonnegative inputs); result valid in lane 63.
__device__ __forceinline__ float wave_max63(float x) {
  x = fmaxf(x, DPPMOV(x, 0x111));
  x = fmaxf(x, DPPMOV(x, 0x112));
  x = fmaxf(x, DPPMOV(x, 0x114));
  x = fmaxf(x, DPPMOV(x, 0x118));
  x = fmaxf(x, DPPMOV(x, 0x142));
  x = fmaxf(x, DPPMOV(x, 0x143));
  return x;
}
// lane n <- lane n-1 (DPP wave_shr:1). Lane 0 <- 0 (additive identity).
__device__ __forceinline__ float wave_shr1_zero(float x) {
  int r = __builtin_amdgcn_update_dpp(0, __float_as_int(x), 0x138, 0xF, 0xF,
                                      false);
  return __int_as_float(r);
}
// lane n <- lane n+1 (DPP wave_shl:1). Lane 63 <- 0.
__device__ __forceinline__ float wave_shl1_zero(float x) {
  int r = __builtin_amdgcn_update_dpp(0, __float_as_int(x), 0x130, 0xF, 0xF,
                                      false);
  return __int_as_float(r);
}

// One row-pair per wave (2 rows of V=512 logits, 4 KB contiguous), wave index
// linear in acts memory order; 16 waves (1024 threads) per block to amortize
// block dispatch/retire. Max-free softmax denominator (DPP reduction); stores
// LINEAR-domain scaled probs diagonal-major:
//   blankD[b][t+u+1][u]   = e^blank_logit / sum * 2^9
//   emitD [b][t+u+1][u+1] = e^label_logit / sum * 2^9
// Unwritten slots are pre-zeroed (memset) = additive identity.
__global__ __launch_bounds__(1024) void lse_kernel(
    const float* __restrict__ acts, const int* __restrict__ labels,
    float* __restrict__ blankD, float* __restrict__ emitD) {
  const int wv = blockIdx.x * 16 + (threadIdx.x >> 6);
  const int lane = threadIdx.x & 63;
  const int r0 = wv * 2;  // row = (b*T + t)*U + u
  const int r1 = r0 + 1;
  const floatx4* p0 = (const floatx4*)(acts + (size_t)r0 * V_);
  const floatx4* p1 = (const floatx4*)(acts + (size_t)r1 * V_);
  floatx4 a0 = p0[lane];
  floatx4 a1 = p0[lane + 64];
  floatx4 c0 = p1[lane];
  floatx4 c1 = p1[lane + 64];
  float s0 = __builtin_exp2f(a0.x * LOG2E) + __builtin_exp2f(a0.y * LOG2E) +
             __builtin_exp2f(a0.z * LOG2E) + __builtin_exp2f(a0.w * LOG2E) +
             __builtin_exp2f(a1.x * LOG2E) + __builtin_exp2f(a1.y * LOG2E) +
             __builtin_exp2f(a1.z * LOG2E) + __builtin_exp2f(a1.w * LOG2E);
  float s1 = __builtin_exp2f(c0.x * LOG2E) + __builtin_exp2f(c0.y * LOG2E) +
             __builtin_exp2f(c0.z * LOG2E) + __builtin_exp2f(c0.w * LOG2E) +
             __builtin_exp2f(c1.x * LOG2E) + __builtin_exp2f(c1.y * LOG2E) +
             __builtin_exp2f(c1.z * LOG2E) + __builtin_exp2f(c1.w * LOG2E);
  s0 = readlane63(wave_sum63(s0));  // uniform across the wave
  s1 = readlane63(wave_sum63(s1));

#define EMIT_ROW(r, v0, v1, ssum)                                             \
  {                                                                           \
    const int u = (r) % U_;                                                   \
    const int bt = (r) / U_;                                                  \
    const int t = bt % T_;                                                    \
    const int b = bt / T_;                                                    \
    float emitv = 0.0f;                                                       \
    if (u < UM1) {                                                            \
      int e = labels[b * UM1 + u]; /* in [1, V) */                            \
      floatx4 sel = (e < 256) ? v0 : v1;                                      \
      int k = e & 3;                                                          \
      float cand =                                                            \
          (k == 0) ? sel.x : (k == 1) ? sel.y : (k == 2) ? sel.z : sel.w;     \
      emitv = __shfl(cand, (e & 255) >> 2);                                   \
    }                                                                         \
    if (lane == 0) {                                                          \
      const float rs = CS * __builtin_amdgcn_rcpf(ssum);                      \
      blankD[((size_t)b * DALLOC + (t + u + 1)) * DSTR + u] =                 \
          __builtin_exp2f(v0.x * LOG2E) * rs;                                 \
      if (u < UM1)                                                            \
        emitD[((size_t)b * DALLOC + (t + u + 1)) * DSTR + (u + 1)] =          \
            __builtin_exp2f(emitv * LOG2E) * rs;                              \
    }                                                                         \
  }

  EMIT_ROW(r0, a0, a1, s0)
  EMIT_ROW(r1, c0, c1, s1)
#undef EMIT_ROW
}

// Bidirectional linear-domain DP with fused combine. Blocks 0..7: forward
// alpha; 8..15: backward beta. Each block writes its meeting state; the
// SECOND finisher per example (flag handshake, order-independent result)
// computes the final loss. Recurrence chain is pure dpp+mul+fma.
__global__ __launch_bounds__(64, 1) void dp_kernel(
    const float* __restrict__ blankD, const float* __restrict__ emitD,
    const int* __restrict__ act_lens, const int* __restrict__ label_lens,
    float* __restrict__ stateA, float* __restrict__ stateB,
    int* __restrict__ flags, float* __restrict__ out) {
  __shared__ float lds[2][2][CH][DSTR];  // 128 KB
  const int bid = blockIdx.x;
  const int b = bid & 7;
  const bool fwd = (bid < 8);
  const int lane = threadIdx.x;
  const int tl1 = act_lens[b] - 1;
  const int ulen = label_lens[b];
  const int dtar = tl1 + ulen;
  const int dmid = dtar >> 1;
  const floatx4* g4B = (const floatx4*)(blankD + (size_t)b * DALLOC * DSTR);
  const floatx4* g4E = (const floatx4*)(emitD + (size_t)b * DALLOC * DSTR);
  floatx4 rB[16], rE[16];
  float xE, xO, S = 0.0f, cE = 0.0f, cO = 0.0f, capS = 0.0f;

  if (fwd) {
    // ---------------- forward: alpha; capture at diagonal dmid ------------
    const int ccap = (dmid - 1) >> 5;  // chunk containing d == dmid
#pragma unroll
    for (int j = 0; j < 16; ++j) {
      rB[j] = g4B[32 + j * 64 + lane];  // chunk 0 = rows 1..32
      rE[j] = g4E[32 + j * 64 + lane];
    }
    {
      floatx4* lB4 = (floatx4*)&lds[0][0][0][0];
      floatx4* lE4 = (floatx4*)&lds[0][1][0][0];
#pragma unroll
      for (int j = 0; j < 16; ++j) {
        lB4[j * 64 + lane] = rB[j];
        lE4[j * 64 + lane] = rE[j];
      }
    }
    xE = (lane == 0) ? 1.0f : 0.0f;  // alpha[0,0] = 1 at diagonal 0
    xO = 0.0f;
    for (int c = 0; c < NCHD; ++c) {
      const int buf = c & 1;
      const int nb = ((c + 1) * CH + 1) * 32;
#pragma unroll
      for (int j = 0; j < 16; ++j) {
        rB[j] = g4B[(size_t)nb + j * 64 + lane];
        rE[j] = g4E[(size_t)nb + j * 64 + lane];
      }
      const floatx2* lB2 = (const floatx2*)&lds[buf][0][0][0];
      const floatx2* lE2 = (const floatx2*)&lds[buf][1][0][0];
      floatx2 pB[8], pE[8];
#pragma unroll
      for (int k = 0; k < 8; ++k) {
        pB[k] = lB2[k * 64 + lane];
        pE[k] = lE2[k * 64 + lane];
      }
      const int dbase = c * CH + 1;
#pragma unroll
      for (int k = 0; k < CH; ++k) {
        const int d = dbase + k;
        const floatx2 Bv = pB[k & 7];
        const floatx2 Ev = pE[k & 7];
        if (k + 8 < CH) {
          pB[k & 7] = lB2[(k + 8) * 64 + lane];
          pE[k & 7] = lE2[(k + 8) * 64 + lane];
        }
        const float xm1E = wave_shr1_zero(xO);  // col uE-1, prev diagonal
        const float nxE = __builtin_fmaf(xE, Bv.x, xm1E * Ev.x);
        const float nxO = __builtin_fmaf(xO, Bv.y, xE * Ev.y);
        const bool cap = (d == dmid);  // off-chain capture
        cE = cap ? nxE : cE;
        cO = cap ? nxO : cO;
        xE = nxE;
        xO = nxO;
      }
      if (c == ccap) capS = S;  // scales applied before the capture chunk
      float m = readlane63(wave_max63(fmaxf(xE, xO)));
      if (m > 0.0f) {
        const float ex = floorf(__builtin_log2f(m));
        const float sc = __builtin_exp2f(-ex);
        xE *= sc;
        xO *= sc;
        S += ex;
      }
      floatx4* wB4 = (floatx4*)&lds[buf ^ 1][0][0][0];
      floatx4* wE4 = (floatx4*)&lds[buf ^ 1][1][0][0];
#pragma unroll
      for (int j = 0; j < 16; ++j) {
        wB4[j * 64 + lane] = rB[j];
        wE4[j * 64 + lane] = rE[j];
      }
    }
    float* sA = stateA + b * 132;
    ((floatx2*)sA)[lane] = floatx2{cE, cO};
    if (lane == 0) sA[128] = capS;
  } else {
    // ---------------- backward: beta; capture at stage smax ---------------
    const int smax = dtar - 1 - dmid;
    const int ccap = smax >> 5;
    const int R00 = dtar - 31;  // chunk 0 rows [dtar-31, dtar]
#pragma unroll
    for (int j = 0; j < 16; ++j) {
      rB[j] = g4B[(size_t)R00 * 32 + j * 64 + lane];
      rE[j] = g4E[(size_t)R00 * 32 + j * 64 + lane];
    }
    {
      floatx4* lB4 = (floatx4*)&lds[0][0][0][0];
      floatx4* lE4 = (floatx4*)&lds[0][1][0][0];
#pragma unroll
      for (int j = 0; j < 16; ++j) {
        lB4[j * 64 + lane] = rB[j];
        lE4[j * 64 + lane] = rE[j];
      }
    }
    const float seed = blankD[((size_t)b * DALLOC + dtar + 1) * DSTR + ulen];
    xE = (lane == (ulen >> 1) && !(ulen & 1)) ? seed : 0.0f;
    xO = (lane == (ulen >> 1) && (ulen & 1)) ? seed : 0.0f;
    for (int c = 0; c < NCHD; ++c) {
      const int buf = c & 1;
      const int R0n = max(R00 - 32 * (c + 1), 0);
#pragma unroll
      for (int j = 0; j < 16; ++j) {
        rB[j] = g4B[(size_t)R0n * 32 + j * 64 + lane];
        rE[j] = g4E[(size_t)R0n * 32 + j * 64 + lane];
      }
      const floatx2* lB2 = (const floatx2*)&lds[buf][0][0][0];
      const floatx2* lE2 = (const floatx2*)&lds[buf][1][0][0];
      floatx2 pB[8], pE[8];
#pragma unroll
      for (int k = 0; k < 8; ++k) {  // slots descending: 31..24
        pB[k] = lB2[(31 - k) * 64 + lane];
        pE[k] = lE2[(31 - k) * 64 + lane];
      }
#pragma unroll
      for (int k = 0; k < CH; ++k) {
        const int s = c * CH + k;
        const floatx2 Bv = pB[k & 7];
        const floatx2 Ev = pE[k & 7];
        if (k + 8 < CH) {
          pB[k & 7] = lB2[(31 - (k + 8)) * 64 + lane];
          pE[k & 7] = lE2[(31 - (k + 8)) * 64 + lane];
        }
        const float tO = wave_shl1_zero(Ev.x * xE);  // lane l+1: Em*beta
        const float nxE = __builtin_fmaf(xE, Bv.x, Ev.y * xO);
        const float nxO = __builtin_fmaf(xO, Bv.y, tO);
        const bool cap = (s == smax);  // off-chain capture
        cE = cap ? nxE : cE;
        cO = cap ? nxO : cO;
        xE = nxE;
        xO = nxO;
      }
      if (c == ccap) capS = S;
      float m = readlane63(wave_max63(fmaxf(xE, xO)));
      if (m > 0.0f) {
        const float ex = floorf(__builtin_log2f(m));
        const float sc = __builtin_exp2f(-ex);
        xE *= sc;
        xO *= sc;
        S += ex;
      }
      floatx4* wB4 = (floatx4*)&lds[buf ^ 1][0][0][0];
      floatx4* wE4 = (floatx4*)&lds[buf ^ 1][1][0][0];
#pragma unroll
      for (int j = 0; j < 16; ++j) {
        wB4[j * 64 + lane] = rB[j];
        wE4[j * 64 + lane] = rE[j];
      }
    }
    float* sB = stateB + b * 132;
    ((floatx2*)sB)[lane] = floatx2{cE, cO};
    if (lane == 0) sB[128] = capS;
  }

  // ---- fused combine: second finisher per example does the dot + log ----
  __threadfence();  // release: state visible device-wide before flag bump
  int old = 0;
  if (lane == 0) old = atomicAdd(&flags[b], 1);
  old = __shfl(old, 0);
  if (old == 1) {
    __threadfence();  // acquire: other block's state now safe to read
    const float* sA = stateA + b * 132;
    const float* sB = stateB + b * 132;
    const floatx2 a = ((const floatx2*)sA)[lane];
    const floatx2 bb = ((const floatx2*)sB)[lane];
    float p = readlane63(wave_sum63(a.x * bb.x + a.y * bb.y));
    if (lane == 0) {
      out[b] = -((__builtin_log2f(p) + sA[128] + sB[128] -
                  9.0f * (float)(dtar + 1)) *
                 LN2);
    }
  }
}

extern "C" void kernel_launch(void* const* d_in, const int* in_sizes, int n_in,
                              void* d_out, int out_size, void* d_ws, size_t ws_size,
                              hipStream_t stream) {
  const float* acts = (const float*)d_in[0];
  const int* labels = (const int*)d_in[1];
  const int* act_lens = (const int*)d_in[2];
  const int* label_lens = (const int*)d_in[3];
  float* out = (float*)d_out;
  // ws layout: [flags 32 ints][blankD][emitD][stateA][stateB]
  int* flags = (int*)d_ws;
  float* blankD = (float*)d_ws + 32;                    // B*DALLOC*DSTR floats
  float* emitD = blankD + (size_t)B_ * DALLOC * DSTR;   // B*DALLOC*DSTR floats
  float* stateA = emitD + (size_t)B_ * DALLOC * DSTR;   // B*132 floats
  float* stateB = stateA + B_ * 132;                    // B*132 floats
  // Zero flags + staging arrays in one memset (flags MUST reset every call).
  hipMemsetAsync(d_ws, 0,
                 (32 + (size_t)2 * B_ * DALLOC * DSTR) * sizeof(float),
                 stream);
  const int nunits = B_ * T_ * U_ / 2;  // 103,424 row-pairs (div by 16)
  lse_kernel<<<nunits / 16, 1024, 0, stream>>>(acts, labels, blankD, emitD);
  dp_kernel<<<16, 64, 0, stream>>>(blankD, emitD, act_lens, label_lens,
                                   stateA, stateB, flags, out);
}

// Round 18
// 93.962 us; speedup vs baseline: 1.0839x; 1.0486x over previous
//
#include <hip/hip_runtime.h>

#define B_ 8
#define T_ 256
#define U_ 101
#define V_ 512
#define UM1 (U_ - 1)
#define DSTR 128    // floats per diagonal row (u-index stride)
#define DALLOC 360  // diagonals allocated (max row read = 356)
#define CH 32       // DP stages per LDS chunk
#define NCHD 6      // chunks per direction (6*32 = 192 >= ceil(355/2)+1)
#define CS 512.0f   // 2^9 per-step growth factor baked into staged probs
#define LOG2E 1.4426950408889634f
#define LN2 0.6931471805599453f

typedef float floatx4 __attribute__((ext_vector_type(4)));
typedef float floatx2 __attribute__((ext_vector_type(2)));

// DPP move with bound_ctrl=1 (out-of-range lanes read 0).
#define DPPMOV(x, ctrl)                                                     \
  __int_as_float(__builtin_amdgcn_update_dpp(0, __float_as_int(x), (ctrl),  \
                                             0xF, 0xF, true))

__device__ __forceinline__ float readlane63(float x) {
  return __int_as_float(__builtin_amdgcn_readlane(__float_as_int(x), 63));
}
// Full-wave sum via DPP (VALU-latency); result valid in lane 63.
__device__ __forceinline__ float wave_sum63(float x) {
  x += DPPMOV(x, 0x111);  // row_shr:1
  x += DPPMOV(x, 0x112);  // row_shr:2
  x += DPPMOV(x, 0x114);  // row_shr:4
  x += DPPMOV(x, 0x118);  // row_shr:8
  x += DPPMOV(x, 0x142);  // row_bcast:15
  x += DPPMOV(x, 0x143);  // row_bcast:31
  return x;
}
// Full-wave max via DPP (nonnegative inputs); result valid in lane 63.
__device__ __forceinline__ float wave_max63(float x) {
  x = fmaxf(x, DPPMOV(x, 0x111));
  x = fmaxf(x, DPPMOV(x, 0x112));
  x = fmaxf(x, DPPMOV(x, 0x114));
  x = fmaxf(x, DPPMOV(x, 0x118));
  x = fmaxf(x, DPPMOV(x, 0x142));
  x = fmaxf(x, DPPMOV(x, 0x143));
  return x;
}
// lane n <- lane n-1 (DPP wave_shr:1). Lane 0 <- 0 (additive identity).
__device__ __forceinline__ float wave_shr1_zero(float x) {
  int r = __builtin_amdgcn_update_dpp(0, __float_as_int(x), 0x138, 0xF, 0xF,
                                      false);
  return __int_as_float(r);
}
// lane n <- lane n+1 (DPP wave_shl:1). Lane 63 <- 0.
__device__ __forceinline__ float wave_shl1_zero(float x) {
  int r = __builtin_amdgcn_update_dpp(0, __float_as_int(x), 0x130, 0xF, 0xF,
                                      false);
  return __int_as_float(r);
}

// One row-pair per wave (2 rows of V=512 logits, 4 KB contiguous), wave index
// linear in acts memory order, 4 waves/block. Max-free softmax denominator
// (DPP reduction); stores LINEAR-domain scaled probs diagonal-major:
//   blankD[b][t+u+1][u]   = e^blank_logit / sum * 2^9
//   emitD [b][t+u+1][u+1] = e^label_logit / sum * 2^9
// Unwritten slots are pre-zeroed (memset) = additive identity.
__global__ __launch_bounds__(256) void lse_kernel(
    const float* __restrict__ acts, const int* __restrict__ labels,
    float* __restrict__ blankD, float* __restrict__ emitD) {
  const int wv = blockIdx.x * 4 + (threadIdx.x >> 6);
  const int lane = threadIdx.x & 63;
  const int r0 = wv * 2;  // row = (b*T + t)*U + u
  const int r1 = r0 + 1;
  const floatx4* p0 = (const floatx4*)(acts + (size_t)r0 * V_);
  const floatx4* p1 = (const floatx4*)(acts + (size_t)r1 * V_);
  floatx4 a0 = p0[lane];
  floatx4 a1 = p0[lane + 64];
  floatx4 c0 = p1[lane];
  floatx4 c1 = p1[lane + 64];
  float s0 = __builtin_exp2f(a0.x * LOG2E) + __builtin_exp2f(a0.y * LOG2E) +
             __builtin_exp2f(a0.z * LOG2E) + __builtin_exp2f(a0.w * LOG2E) +
             __builtin_exp2f(a1.x * LOG2E) + __builtin_exp2f(a1.y * LOG2E) +
             __builtin_exp2f(a1.z * LOG2E) + __builtin_exp2f(a1.w * LOG2E);
  float s1 = __builtin_exp2f(c0.x * LOG2E) + __builtin_exp2f(c0.y * LOG2E) +
             __builtin_exp2f(c0.z * LOG2E) + __builtin_exp2f(c0.w * LOG2E) +
             __builtin_exp2f(c1.x * LOG2E) + __builtin_exp2f(c1.y * LOG2E) +
             __builtin_exp2f(c1.z * LOG2E) + __builtin_exp2f(c1.w * LOG2E);
  s0 = readlane63(wave_sum63(s0));  // uniform across the wave
  s1 = readlane63(wave_sum63(s1));

#define EMIT_ROW(r, v0, v1, ssum)                                             \
  {                                                                           \
    const int u = (r) % U_;                                                   \
    const int bt = (r) / U_;                                                  \
    const int t = bt % T_;                                                    \
    const int b = bt / T_;                                                    \
    float emitv = 0.0f;                                                       \
    if (u < UM1) {                                                            \
      int e = labels[b * UM1 + u]; /* in [1, V) */                            \
      floatx4 sel = (e < 256) ? v0 : v1;                                      \
      int k = e & 3;                                                          \
      float cand =                                                            \
          (k == 0) ? sel.x : (k == 1) ? sel.y : (k == 2) ? sel.z : sel.w;     \
      emitv = __shfl(cand, (e & 255) >> 2);                                   \
    }                                                                         \
    if (lane == 0) {                                                          \
      const float rs = CS * __builtin_amdgcn_rcpf(ssum);                      \
      blankD[((size_t)b * DALLOC + (t + u + 1)) * DSTR + u] =                 \
          __builtin_exp2f(v0.x * LOG2E) * rs;                                 \
      if (u < UM1)                                                            \
        emitD[((size_t)b * DALLOC + (t + u + 1)) * DSTR + (u + 1)] =          \
            __builtin_exp2f(emitv * LOG2E) * rs;                              \
    }                                                                         \
  }

  EMIT_ROW(r0, a0, a1, s0)
  EMIT_ROW(r1, c0, c1, s1)
#undef EMIT_ROW
}

// Bidirectional linear-domain DP with fused combine. Blocks 0..7: forward
// alpha; 8..15: backward beta. Each block writes its meeting state; the
// SECOND finisher per example (flag handshake, order-independent result)
// computes the final loss. Recurrence chain is pure dpp+mul+fma.
__global__ __launch_bounds__(64, 1) void dp_kernel(
    const float* __restrict__ blankD, const float* __restrict__ emitD,
    const int* __restrict__ act_lens, const int* __restrict__ label_lens,
    float* __restrict__ stateA, float* __restrict__ stateB,
    int* __restrict__ flags, float* __restrict__ out) {
  __shared__ float lds[2][2][CH][DSTR];  // 128 KB
  const int bid = blockIdx.x;
  const int b = bid & 7;
  const bool fwd = (bid < 8);
  const int lane = threadIdx.x;
  const int tl1 = act_lens[b] - 1;
  const int ulen = label_lens[b];
  const int dtar = tl1 + ulen;
  const int dmid = dtar >> 1;
  const floatx4* g4B = (const floatx4*)(blankD + (size_t)b * DALLOC * DSTR);
  const floatx4* g4E = (const floatx4*)(emitD + (size_t)b * DALLOC * DSTR);
  floatx4 rB[16], rE[16];
  float xE, xO, S = 0.0f, cE = 0.0f, cO = 0.0f, capS = 0.0f;

  if (fwd) {
    // ---------------- forward: alpha; capture at diagonal dmid ------------
    const int ccap = (dmid - 1) >> 5;  // chunk containing d == dmid
#pragma unroll
    for (int j = 0; j < 16; ++j) {
      rB[j] = g4B[32 + j * 64 + lane];  // chunk 0 = rows 1..32
      rE[j] = g4E[32 + j * 64 + lane];
    }
    {
      floatx4* lB4 = (floatx4*)&lds[0][0][0][0];
      floatx4* lE4 = (floatx4*)&lds[0][1][0][0];
#pragma unroll
      for (int j = 0; j < 16; ++j) {
        lB4[j * 64 + lane] = rB[j];
        lE4[j * 64 + lane] = rE[j];
      }
    }
    xE = (lane == 0) ? 1.0f : 0.0f;  // alpha[0,0] = 1 at diagonal 0
    xO = 0.0f;
    for (int c = 0; c < NCHD; ++c) {
      const int buf = c & 1;
      const int nb = ((c + 1) * CH + 1) * 32;
#pragma unroll
      for (int j = 0; j < 16; ++j) {
        rB[j] = g4B[(size_t)nb + j * 64 + lane];
        rE[j] = g4E[(size_t)nb + j * 64 + lane];
      }
      const floatx2* lB2 = (const floatx2*)&lds[buf][0][0][0];
      const floatx2* lE2 = (const floatx2*)&lds[buf][1][0][0];
      floatx2 pB[8], pE[8];
#pragma unroll
      for (int k = 0; k < 8; ++k) {
        pB[k] = lB2[k * 64 + lane];
        pE[k] = lE2[k * 64 + lane];
      }
      const int dbase = c * CH + 1;
#pragma unroll
      for (int k = 0; k < CH; ++k) {
        const int d = dbase + k;
        const floatx2 Bv = pB[k & 7];
        const floatx2 Ev = pE[k & 7];
        if (k + 8 < CH) {
          pB[k & 7] = lB2[(k + 8) * 64 + lane];
          pE[k & 7] = lE2[(k + 8) * 64 + lane];
        }
        const float xm1E = wave_shr1_zero(xO);  // col uE-1, prev diagonal
        const float nxE = __builtin_fmaf(xE, Bv.x, xm1E * Ev.x);
        const float nxO = __builtin_fmaf(xO, Bv.y, xE * Ev.y);
        const bool cap = (d == dmid);  // off-chain capture
        cE = cap ? nxE : cE;
        cO = cap ? nxO : cO;
        xE = nxE;
        xO = nxO;
      }
      if (c == ccap) capS = S;  // scales applied before the capture chunk
      float m = readlane63(wave_max63(fmaxf(xE, xO)));
      if (m > 0.0f) {
        const float ex = floorf(__builtin_log2f(m));
        const float sc = __builtin_exp2f(-ex);
        xE *= sc;
        xO *= sc;
        S += ex;
      }
      floatx4* wB4 = (floatx4*)&lds[buf ^ 1][0][0][0];
      floatx4* wE4 = (floatx4*)&lds[buf ^ 1][1][0][0];
#pragma unroll
      for (int j = 0; j < 16; ++j) {
        wB4[j * 64 + lane] = rB[j];
        wE4[j * 64 + lane] = rE[j];
      }
    }
    float* sA = stateA + b * 132;
    ((floatx2*)sA)[lane] = floatx2{cE, cO};
    if (lane == 0) sA[128] = capS;
  } else {
    // ---------------- backward: beta; capture at stage smax ---------------
    const int smax = dtar - 1 - dmid;
    const int ccap = smax >> 5;
    const int R00 = dtar - 31;  // chunk 0 rows [dtar-31, dtar]
#pragma unroll
    for (int j = 0; j < 16; ++j) {
      rB[j] = g4B[(size_t)R00 * 32 + j * 64 + lane];
      rE[j] = g4E[(size_t)R00 * 32 + j * 64 + lane];
    }
    {
      floatx4* lB4 = (floatx4*)&lds[0][0][0][0];
      floatx4* lE4 = (floatx4*)&lds[0][1][0][0];
#pragma unroll
      for (int j = 0; j < 16; ++j) {
        lB4[j * 64 + lane] = rB[j];
        lE4[j * 64 + lane] = rE[j];
      }
    }
    const float seed = blankD[((size_t)b * DALLOC + dtar + 1) * DSTR + ulen];
    xE = (lane == (ulen >> 1) && !(ulen & 1)) ? seed : 0.0f;
    xO = (lane == (ulen >> 1) && (ulen & 1)) ? seed : 0.0f;
    for (int c = 0; c < NCHD; ++c) {
      const int buf = c & 1;
      const int R0n = max(R00 - 32 * (c + 1), 0);
#pragma unroll
      for (int j = 0; j < 16; ++j) {
        rB[j] = g4B[(size_t)R0n * 32 + j * 64 + lane];
        rE[j] = g4E[(size_t)R0n * 32 + j * 64 + lane];
      }
      const floatx2* lB2 = (const floatx2*)&lds[buf][0][0][0];
      const floatx2* lE2 = (const floatx2*)&lds[buf][1][0][0];
      floatx2 pB[8], pE[8];
#pragma unroll
      for (int k = 0; k < 8; ++k) {  // slots descending: 31..24
        pB[k] = lB2[(31 - k) * 64 + lane];
        pE[k] = lE2[(31 - k) * 64 + lane];
      }
#pragma unroll
      for (int k = 0; k < CH; ++k) {
        const int s = c * CH + k;
        const floatx2 Bv = pB[k & 7];
        const floatx2 Ev = pE[k & 7];
        if (k + 8 < CH) {
          pB[k & 7] = lB2[(31 - (k + 8)) * 64 + lane];
          pE[k & 7] = lE2[(31 - (k + 8)) * 64 + lane];
        }
        const float tO = wave_shl1_zero(Ev.x * xE);  // lane l+1: Em*beta
        const float nxE = __builtin_fmaf(xE, Bv.x, Ev.y * xO);
        const float nxO = __builtin_fmaf(xO, Bv.y, tO);
        const bool cap = (s == smax);  // off-chain capture
        cE = cap ? nxE : cE;
        cO = cap ? nxO : cO;
        xE = nxE;
        xO = nxO;
      }
      if (c == ccap) capS = S;
      float m = readlane63(wave_max63(fmaxf(xE, xO)));
      if (m > 0.0f) {
        const float ex = floorf(__builtin_log2f(m));
        const float sc = __builtin_exp2f(-ex);
        xE *= sc;
        xO *= sc;
        S += ex;
      }
      floatx4* wB4 = (floatx4*)&lds[buf ^ 1][0][0][0];
      floatx4* wE4 = (floatx4*)&lds[buf ^ 1][1][0][0];
#pragma unroll
      for (int j = 0; j < 16; ++j) {
        wB4[j * 64 + lane] = rB[j];
        wE4[j * 64 + lane] = rE[j];
      }
    }
    float* sB = stateB + b * 132;
    ((floatx2*)sB)[lane] = floatx2{cE, cO};
    if (lane == 0) sB[128] = capS;
  }

  // ---- fused combine: second finisher per example does the dot + log ----
  __threadfence();  // release: state visible device-wide before flag bump
  int old = 0;
  if (lane == 0) old = atomicAdd(&flags[b], 1);
  old = __shfl(old, 0);
  if (old == 1) {
    __threadfence();  // acquire: other block's state now safe to read
    const float* sA = stateA + b * 132;
    const float* sB = stateB + b * 132;
    const floatx2 a = ((const floatx2*)sA)[lane];
    const floatx2 bb = ((const floatx2*)sB)[lane];
    float p = readlane63(wave_sum63(a.x * bb.x + a.y * bb.y));
    if (lane == 0) {
      out[b] = -((__builtin_log2f(p) + sA[128] + sB[128] -
                  9.0f * (float)(dtar + 1)) *
                 LN2);
    }
  }
}

extern "C" void kernel_launch(void* const* d_in, const int* in_sizes, int n_in,
                              void* d_out, int out_size, void* d_ws, size_t ws_size,
                              hipStream_t stream) {
  const float* acts = (const float*)d_in[0];
  const int* labels = (const int*)d_in[1];
  const int* act_lens = (const int*)d_in[2];
  const int* label_lens = (const int*)d_in[3];
  float* out = (float*)d_out;
  // ws layout: [flags 32 ints][blankD][emitD][stateA][stateB]
  int* flags = (int*)d_ws;
  float* blankD = (float*)d_ws + 32;                    // B*DALLOC*DSTR floats
  float* emitD = blankD + (size_t)B_ * DALLOC * DSTR;   // B*DALLOC*DSTR floats
  float* stateA = emitD + (size_t)B_ * DALLOC * DSTR;   // B*132 floats
  float* stateB = stateA + B_ * 132;                    // B*132 floats
  // Zero flags + staging arrays in one memset (flags MUST reset every call).
  hipMemsetAsync(d_ws, 0,
                 (32 + (size_t)2 * B_ * DALLOC * DSTR) * sizeof(float),
                 stream);
  const int nwaves2 = B_ * T_ * U_ / 2;  // 103,424 row-pairs (div by 4)
  lse_kernel<<<nwaves2 / 4, 256, 0, stream>>>(acts, labels, blankD, emitD);
  dp_kernel<<<16, 64, 0, stream>>>(blankD, emitD, act_lens, label_lens,
                                   stateA, stateB, flags, out);
}